// Round 7
// baseline (363.641 us; speedup 1.0000x reference)
//
#include <hip/hip_runtime.h>
#include <math.h>

#define NN 50000
#define EPSM 1e-7f
#define BN_EPS 1e-5f
#define NBK 391                 // ceil(50000/128) buckets of 128 nodes

// ---------------- bucket-sorted CSR build (line-coalesced writes) ----------------

// global bucket histogram via LDS pre-reduction; block 0 seeds layer-0 mm/bn
__global__ __launch_bounds__(256) void bucket_hist_kernel(
    const int* __restrict__ dst, int* __restrict__ bhist, int E,
    unsigned* __restrict__ mm0, float* __restrict__ bn0){
  __shared__ int h[NBK];
  int t = threadIdx.x;
  if (blockIdx.x == 0){
    if (t < 64) mm0[t] = 0x7F7FFFFFu;      // colmin seed = FLT_MAX
    else if (t < 128) mm0[t] = 0u;         // colmax seed = 0
    bn0[t] = 0.f;
  }
  for (int i = t; i < NBK; i += 256) h[i] = 0;
  __syncthreads();
  int e0 = blockIdx.x * 4096;
  int cnt = min(4096, E - e0);
  for (int i = t; i < cnt; i += 256) atomicAdd(&h[dst[e0 + i] >> 7], 1);
  __syncthreads();
  for (int i = t; i < NBK; i += 256) if (h[i]) atomicAdd(&bhist[i], h[i]);
}

// one-wave exclusive scan of 391 bucket counts -> bbase[392], gcur
__global__ void bucket_scan_kernel(const int* __restrict__ bhist,
                                   int* __restrict__ bbase, int* __restrict__ gcur){
  int lane = threadIdx.x;   // 64 threads
  int loc[7]; int s = 0;
#pragma unroll
  for (int k = 0; k < 7; ++k){
    int i = lane * 7 + k;
    int v = (i < NBK) ? bhist[i] : 0;
    loc[k] = s; s += v;
  }
  int sc = s;
#pragma unroll
  for (int o = 1; o < 64; o <<= 1){
    int n = __shfl_up(sc, o);
    if (lane >= o) sc += n;
  }
  int exc = sc - s;
#pragma unroll
  for (int k = 0; k < 7; ++k){
    int i = lane * 7 + k;
    if (i < NBK){ bbase[i] = exc + loc[k]; gcur[i] = exc + loc[k]; }
    else if (i == NBK) bbase[i] = exc + loc[k];   // total == E
  }
}

// pass 1: LDS-reorder 4096-edge chunks by bucket, burst-write packed (dst<<16|src)
__global__ __launch_bounds__(256) void bucket_scatter_kernel(
    const int* __restrict__ src, const int* __restrict__ dst,
    int* __restrict__ gcur, unsigned* __restrict__ packed_g, int E){
  __shared__ int hist[NBK], offs[NBK], gb[NBK], curk[NBK];
  __shared__ unsigned stage[4096];
  __shared__ int gpos[4096];
  int t = threadIdx.x;
  for (int i = t; i < NBK; i += 256) hist[i] = 0;
  __syncthreads();
  int e0 = blockIdx.x * 4096;
  int cnt = min(4096, E - e0);
  unsigned pk[16]; int bk[16];
  int nmine = 0;
  for (int i = t; i < cnt; i += 256){
    int d = dst[e0 + i], s = src[e0 + i];
    pk[nmine] = ((unsigned)d << 16) | (unsigned)s;
    bk[nmine] = d >> 7;
    atomicAdd(&hist[bk[nmine]], 1);
    ++nmine;
  }
  __syncthreads();
  if (t < 64){                      // wave-0 scan of 391 counts (7 per lane)
    int loc[7]; int s = 0;
#pragma unroll
    for (int k = 0; k < 7; ++k){
      int i = t * 7 + k;
      int v = (i < NBK) ? hist[i] : 0;
      loc[k] = s; s += v;
    }
    int sc = s;
#pragma unroll
    for (int o = 1; o < 64; o <<= 1){
      int n = __shfl_up(sc, o);
      if (t >= o) sc += n;
    }
    int exc = sc - s;
#pragma unroll
    for (int k = 0; k < 7; ++k){
      int i = t * 7 + k;
      if (i < NBK) offs[i] = exc + loc[k];
    }
  }
  __syncthreads();
  for (int i = t; i < NBK; i += 256){
    int h = hist[i];
    gb[i] = h ? atomicAdd(&gcur[i], h) : 0;
    curk[i] = offs[i];
  }
  __syncthreads();
  for (int k = 0; k < nmine; ++k){
    int b = bk[k];
    int p = atomicAdd(&curk[b], 1);
    stage[p] = pk[k];
    gpos[p] = gb[b] + (p - offs[b]);
  }
  __syncthreads();
  for (int j = t; j < cnt; j += 256) packed_g[gpos[j]] = stage[j];   // run-coalesced
}

// pass 2: one block per bucket — per-node offsets, start/end, coalesced srcs write
__global__ __launch_bounds__(256) void bucket_place_kernel(
    const unsigned* __restrict__ packed_g, const int* __restrict__ bbase,
    int* __restrict__ start_g, int* __restrict__ end_g,
    unsigned short* __restrict__ srcs_g, int N){
  __shared__ int deg[128], off[128], cur[128];
  __shared__ int sstage[4096];
  int b = blockIdx.x, t = threadIdx.x;
  int beg = bbase[b], cnt = bbase[b + 1] - beg;
  if (t < 128) deg[t] = 0;
  __syncthreads();
  for (int j = t; j < cnt; j += 256)
    atomicAdd(&deg[(packed_g[beg + j] >> 16) & 127], 1);
  __syncthreads();
  if (t < 64){                      // wave-0 scan of 128 (2 per lane)
    int i0 = t * 2;
    int v0 = deg[i0], v1 = deg[i0 + 1];
    int s = v0 + v1;
    int sc = s;
#pragma unroll
    for (int o = 1; o < 64; o <<= 1){
      int n = __shfl_up(sc, o);
      if (t >= o) sc += n;
    }
    int exc = sc - s;
    off[i0] = exc; off[i0 + 1] = exc + v0;
  }
  __syncthreads();
  int node0 = b * 128;
  if (t < 128){
    int node = node0 + t;
    if (node < N){
      start_g[node] = beg + off[t];
      end_g[node] = beg + off[t] + deg[t];
    }
    cur[t] = off[t];
  }
  __syncthreads();
  if (cnt <= 4096){
    for (int j = t; j < cnt; j += 256){
      unsigned p = packed_g[beg + j];
      int lp = atomicAdd(&cur[(p >> 16) & 127], 1);
      sstage[lp] = (int)(p & 0xFFFFu);
    }
    __syncthreads();
    for (int j = t; j < cnt; j += 256)
      srcs_g[beg + j] = (unsigned short)sstage[j];   // coalesced
  } else {                          // freak-bucket fallback (never for random graph)
    for (int j = t; j < cnt; j += 256){
      unsigned p = packed_g[beg + j];
      int lp = atomicAdd(&cur[(p >> 16) & 127], 1);
      srcs_g[beg + lp] = (unsigned short)(p & 0xFFFFu);
    }
  }
}

// ---------------- layer-0 only: split bf16 message table + column min/max ----------
// mh layout: [half][node][32] so each half-table is 3.2 MB (fits one XCD L2).

__global__ __launch_bounds__(256) void colminmax_kernel(
    const float* __restrict__ x, unsigned* __restrict__ mm,
    unsigned short* __restrict__ mh, int N){
  __shared__ unsigned smn[256], smx[256];
  int c = threadIdx.x & 63;
  int half = c >> 5, cc = c & 31;
  unsigned short* mhh = mh + (size_t)half * N * 32;
  int slot = blockIdx.x * 4 + (threadIdx.x >> 6);
  float mx = 0.f, mn = 1e30f;
  for (int r = slot; r < N; r += 256 * 4){
    float m = fmaxf(x[r * 64 + c], 0.f) + EPSM;
    unsigned u = __float_as_uint(m);
    u += 0x7FFFu + ((u >> 16) & 1u);         // RNE to bf16
    unsigned short us = (unsigned short)(u >> 16);
    mhh[r * 32 + cc] = us;
    float mb = __uint_as_float(((unsigned)us) << 16);
    mx = fmaxf(mx, mb);
    mn = fminf(mn, mb);
  }
  smn[threadIdx.x] = __float_as_uint(mn);
  smx[threadIdx.x] = __float_as_uint(mx);
  __syncthreads();
  if (threadIdx.x < 64){
    unsigned a = smn[c], b = smn[c + 64], d = smn[c + 128], e = smn[c + 192];
    atomicMin(&mm[c], min(min(a, b), min(d, e)));
    a = smx[c]; b = smx[c + 64]; d = smx[c + 128]; e = smx[c + 192];
    atomicMax(&mm[64 + c], max(max(a, b), max(d, e)));
  }
}

// ------------- single-pass softmax aggregation, half-channel passes -------------
// gridDim.y = 2 channel halves; wave = 32 channels x 2 edge slots; the half's
// 3.2 MB message table is L2-resident per XCD.

__global__ __launch_bounds__(256) void aggregate_kernel(
    const float* __restrict__ x, const unsigned short* __restrict__ mh,
    const int* __restrict__ start, const int* __restrict__ segend,
    const unsigned short* __restrict__ srcs, const float* __restrict__ tptr,
    int layer, const unsigned* __restrict__ mm, float* __restrict__ h0, int N){
  int node = blockIdx.x * 4 + (threadIdx.x >> 6);
  if (node >= N) return;
  int lane = threadIdx.x & 63;
  int c = lane & 31, slot = lane >> 5;
  int half = blockIdx.y;
  int ch = half * 32 + c;
  const unsigned short* mhh = mh + (size_t)half * N * 32;
  float t = tptr[layer];
  float mn = __uint_as_float(mm[ch]);
  float mx = __uint_as_float(mm[64 + ch]);
  float B = fmaxf(t * mx, t * mn);      // upper bound on logits (any sign of t)
  int beg = start[node], end = segend[node];
  float den0 = 0.f, den1 = 0.f, den2 = 0.f, den3 = 0.f;
  float num0 = 0.f, num1 = 0.f, num2 = 0.f, num3 = 0.f;
  int e = beg + slot;                   // slot 0: even offsets, slot 1: odd
  for (; e + 6 < end; e += 8){
    int s0 = srcs[e], s1 = srcs[e + 2], s2 = srcs[e + 4], s3 = srcs[e + 6];
    float m0 = __uint_as_float(((unsigned)mhh[s0 * 32 + c]) << 16);
    float m1 = __uint_as_float(((unsigned)mhh[s1 * 32 + c]) << 16);
    float m2 = __uint_as_float(((unsigned)mhh[s2 * 32 + c]) << 16);
    float m3 = __uint_as_float(((unsigned)mhh[s3 * 32 + c]) << 16);
    float e0 = __expf(m0 * t - B), e1 = __expf(m1 * t - B);
    float e2 = __expf(m2 * t - B), e3 = __expf(m3 * t - B);
    den0 += e0; num0 += m0 * e0;
    den1 += e1; num1 += m1 * e1;
    den2 += e2; num2 += m2 * e2;
    den3 += e3; num3 += m3 * e3;
  }
  for (; e < end; e += 2){
    int s = srcs[e];
    float m = __uint_as_float(((unsigned)mhh[s * 32 + c]) << 16);
    float ex = __expf(m * t - B);
    den0 += ex; num0 += m * ex;
  }
  float den = (den0 + den1) + (den2 + den3);
  float num = (num0 + num1) + (num2 + num3);
  den += __shfl_xor(den, 32);           // combine the two edge slots
  num += __shfl_xor(num, 32);
  if (slot == 0)
    h0[node * 64 + ch] = num / (den + 1e-16f) + x[node * 64 + ch];
}

// ---------------- MLP ----------------

// h1 = h0 @ W1 + b1 ; fused BN sum/sumsq; layer-0 block 0 seeds next mm/bn
__global__ __launch_bounds__(256) void gemm1_kernel(
    const float* __restrict__ h0, const float* __restrict__ W1,
    const float* __restrict__ b1, float* __restrict__ h1,
    float* __restrict__ bn, int N,
    unsigned* __restrict__ mm_next, float* __restrict__ bn_next){
  __shared__ float a_lds[64 * 68];
  __shared__ float w_lds[64 * 128];
  int t = threadIdx.x;
  if (mm_next != 0 && blockIdx.x == 0){
    if (t < 64) mm_next[t] = 0x7F7FFFFFu;
    else if (t < 128) mm_next[t] = 0u;
    bn_next[t] = 0.f;
  }
  const float4* wg = (const float4*)W1;
  float4* wl = (float4*)w_lds;
#pragma unroll
  for (int i = 0; i < 8; ++i) wl[t + 256 * i] = wg[t + 256 * i];
  int row0 = blockIdx.x * 64;
#pragma unroll
  for (int i = 0; i < 4; ++i){
    int li = t + 256 * i;
    int r = li >> 4, q = li & 15;
    int gr = row0 + r;
    float4 v = make_float4(0.f, 0.f, 0.f, 0.f);
    if (gr < N) v = ((const float4*)h0)[gr * 16 + q];
    *(float4*)&a_lds[r * 68 + q * 4] = v;
  }
  __syncthreads();
  int tc = t & 31, tr = t >> 5;
  float4 bias = ((const float4*)b1)[tc];
  float acc[8][4];
#pragma unroll
  for (int r = 0; r < 8; ++r){
    acc[r][0] = bias.x; acc[r][1] = bias.y; acc[r][2] = bias.z; acc[r][3] = bias.w;
  }
  for (int k = 0; k < 64; k += 4){
    float4 w0 = *(const float4*)&w_lds[(k + 0) * 128 + tc * 4];
    float4 w1 = *(const float4*)&w_lds[(k + 1) * 128 + tc * 4];
    float4 w2 = *(const float4*)&w_lds[(k + 2) * 128 + tc * 4];
    float4 w3 = *(const float4*)&w_lds[(k + 3) * 128 + tc * 4];
#pragma unroll
    for (int r = 0; r < 8; ++r){
      float4 a = *(const float4*)&a_lds[(tr * 8 + r) * 68 + k];
      acc[r][0] += a.x * w0.x + a.y * w1.x + a.z * w2.x + a.w * w3.x;
      acc[r][1] += a.x * w0.y + a.y * w1.y + a.z * w2.y + a.w * w3.y;
      acc[r][2] += a.x * w0.z + a.y * w1.z + a.z * w2.z + a.w * w3.z;
      acc[r][3] += a.x * w0.w + a.y * w1.w + a.z * w2.w + a.w * w3.w;
    }
  }
  float s[4] = {0.f, 0.f, 0.f, 0.f}, s2[4] = {0.f, 0.f, 0.f, 0.f};
#pragma unroll
  for (int r = 0; r < 8; ++r){
    int gr = row0 + tr * 8 + r;
    if (gr < N){
      *(float4*)&h1[gr * 128 + tc * 4] =
          make_float4(acc[r][0], acc[r][1], acc[r][2], acc[r][3]);
#pragma unroll
      for (int j = 0; j < 4; ++j){ s[j] += acc[r][j]; s2[j] += acc[r][j] * acc[r][j]; }
    }
  }
  __syncthreads();
  float* red = a_lds;
  if (t < 256){ red[t] = 0.f; }
  __syncthreads();
#pragma unroll
  for (int j = 0; j < 4; ++j){
    atomicAdd(&red[tc * 4 + j], s[j]);
    atomicAdd(&red[128 + tc * 4 + j], s2[j]);
  }
  __syncthreads();
  if (t < 256) atomicAdd(&bn[t], red[t]);
}

// xout = relu( relu(BN(h1)) @ W2 + b2 ). Layer 0 also emits next layer's split
// bf16 message table (xout >= 0 so m = xout + eps) and column min/max.
__global__ __launch_bounds__(256) void gemm2_kernel(
    const float* __restrict__ h1, const float* __restrict__ bn,
    const float* __restrict__ gamma, const float* __restrict__ beta, int layer,
    const float* __restrict__ W2, const float* __restrict__ b2,
    float* __restrict__ xout, int N,
    unsigned* __restrict__ mm_next, unsigned short* __restrict__ mh_next){
  __shared__ float a_lds[64 * 132];
  __shared__ float w_lds[128 * 68];
  __shared__ float ss[256];     // scale[128], shift[128]
  __shared__ unsigned smn[64], smx[64];
  int t = threadIdx.x;
  if (t < 128){
    float mean = bn[t] * (1.f / (float)N);
    float var = bn[128 + t] * (1.f / (float)N) - mean * mean;
    var = fmaxf(var, 0.f);
    float sc = gamma[layer * 128 + t] / sqrtf(var + BN_EPS);
    ss[t] = sc;
    ss[128 + t] = beta[layer * 128 + t] - mean * sc;
  }
  if (t < 64){ smn[t] = 0x7F7FFFFFu; smx[t] = 0u; }
  const float4* wg = (const float4*)W2;
#pragma unroll
  for (int i = 0; i < 8; ++i){
    int li = t + 256 * i;
    int k = li >> 4, q = li & 15;
    *(float4*)&w_lds[k * 68 + q * 4] = wg[li];
  }
  __syncthreads();
  int row0 = blockIdx.x * 64;
#pragma unroll
  for (int i = 0; i < 8; ++i){
    int li = t + 256 * i;
    int r = li >> 5, q = li & 31;
    int gr = row0 + r;
    float4 v = make_float4(0.f, 0.f, 0.f, 0.f);
    if (gr < N) v = ((const float4*)h1)[gr * 32 + q];
    float4 sc = *(const float4*)&ss[q * 4];
    float4 sh = *(const float4*)&ss[128 + q * 4];
    v.x = fmaxf(v.x * sc.x + sh.x, 0.f);
    v.y = fmaxf(v.y * sc.y + sh.y, 0.f);
    v.z = fmaxf(v.z * sc.z + sh.z, 0.f);
    v.w = fmaxf(v.w * sc.w + sh.w, 0.f);
    *(float4*)&a_lds[r * 132 + q * 4] = v;
  }
  __syncthreads();
  int tc = t & 15, tr = t >> 4;
  float4 bias = ((const float4*)b2)[tc];
  float acc[4][4];
#pragma unroll
  for (int r = 0; r < 4; ++r){
    acc[r][0] = bias.x; acc[r][1] = bias.y; acc[r][2] = bias.z; acc[r][3] = bias.w;
  }
  for (int k = 0; k < 128; k += 4){
    float4 w0 = *(const float4*)&w_lds[(k + 0) * 68 + tc * 4];
    float4 w1 = *(const float4*)&w_lds[(k + 1) * 68 + tc * 4];
    float4 w2 = *(const float4*)&w_lds[(k + 2) * 68 + tc * 4];
    float4 w3 = *(const float4*)&w_lds[(k + 3) * 68 + tc * 4];
#pragma unroll
    for (int r = 0; r < 4; ++r){
      float4 a = *(const float4*)&a_lds[(tr * 4 + r) * 132 + k];
      acc[r][0] += a.x * w0.x + a.y * w1.x + a.z * w2.x + a.w * w3.x;
      acc[r][1] += a.x * w0.y + a.y * w1.y + a.z * w2.y + a.w * w3.y;
      acc[r][2] += a.x * w0.z + a.y * w1.z + a.z * w2.z + a.w * w3.z;
      acc[r][3] += a.x * w0.w + a.y * w1.w + a.z * w2.w + a.w * w3.w;
    }
  }
  unsigned mnv[4] = {0x7F7FFFFFu, 0x7F7FFFFFu, 0x7F7FFFFFu, 0x7F7FFFFFu};
  unsigned mxv[4] = {0u, 0u, 0u, 0u};
#pragma unroll
  for (int r = 0; r < 4; ++r){
    int gr = row0 + tr * 4 + r;
    if (gr < N){
      float o0 = fmaxf(acc[r][0], 0.f), o1 = fmaxf(acc[r][1], 0.f);
      float o2 = fmaxf(acc[r][2], 0.f), o3 = fmaxf(acc[r][3], 0.f);
      *(float4*)&xout[gr * 64 + tc * 4] = make_float4(o0, o1, o2, o3);
      if (mh_next != 0){
        unsigned us[4];
        float ov[4] = {o0, o1, o2, o3};
#pragma unroll
        for (int j = 0; j < 4; ++j){
          unsigned u = __float_as_uint(ov[j] + EPSM);
          u += 0x7FFFu + ((u >> 16) & 1u);       // RNE to bf16
          us[j] = u >> 16;
          unsigned fb = us[j] << 16;              // rounded value bits (positive)
          mnv[j] = min(mnv[j], fb);
          mxv[j] = max(mxv[j], fb);
        }
        // split layout: half = tc>>3, within-half uint2 index = tc&7
        unsigned short* mh_half = mh_next + (size_t)(tc >> 3) * N * 32;
        ((uint2*)mh_half)[gr * 8 + (tc & 7)] =
            make_uint2(us[0] | (us[1] << 16), us[2] | (us[3] << 16));
      }
    }
  }
  if (mh_next != 0){
    __syncthreads();
#pragma unroll
    for (int j = 0; j < 4; ++j){
      atomicMin(&smn[tc * 4 + j], mnv[j]);
      atomicMax(&smx[tc * 4 + j], mxv[j]);
    }
    __syncthreads();
    if (t < 64){
      atomicMin(&mm_next[t], smn[t]);
      atomicMax(&mm_next[64 + t], smx[t]);
    }
  }
}

extern "C" void kernel_launch(void* const* d_in, const int* in_sizes, int n_in,
                              void* d_out, int out_size, void* d_ws, size_t ws_size,
                              hipStream_t stream) {
  const float* x0    = (const float*)d_in[0];
  const int*   ei    = (const int*)d_in[1];
  const float* W1    = (const float*)d_in[2];
  const float* b1    = (const float*)d_in[3];
  const float* gamma = (const float*)d_in[4];
  const float* beta  = (const float*)d_in[5];
  const float* W2    = (const float*)d_in[6];
  const float* b2    = (const float*)d_in[7];
  const float* tptr  = (const float*)d_in[8];

  const int N = NN;
  const int E = in_sizes[1] / 2;
  const int* src = ei;
  const int* dst = ei + E;

  float* ws  = (float*)d_ws;
  float* h0  = ws;                        // N*64
  float* h1  = h0 + N * 64;               // N*128
  float* bn0 = h1 + N * 128;              // 256
  float* bn1 = bn0 + 256;                 // 256
  unsigned* mm0 = (unsigned*)(bn1 + 256); // 128
  unsigned* mm1 = mm0 + 128;              // 128
  unsigned short* mh = (unsigned short*)(mm1 + 128);  // N*64 bf16, [2][N][32]
  int* bhist = (int*)(mh + N * 64);       // NBK
  int* bbase = bhist + NBK;               // NBK+1
  int* gcur  = bbase + NBK + 1;           // NBK
  int* start = gcur + NBK;                // N
  int* segend = start + N;                // N
  unsigned* packed = (unsigned*)(segend + N);  // E
  unsigned short* srcs = (unsigned short*)(packed + E);  // E

  float* out = (float*)d_out;

  const int row_blocks = (N + 63) / 64;
  const int chunk_blocks = (E + 4095) / 4096;
  const dim3 agg_grid((N + 3) / 4, 2);

  // ---- bucket-sorted CSR build (edge structure is layer-invariant) ----
  hipMemsetAsync(bhist, 0, NBK * sizeof(int), stream);
  bucket_hist_kernel<<<chunk_blocks, 256, 0, stream>>>(dst, bhist, E, mm0, bn0);
  bucket_scan_kernel<<<1, 64, 0, stream>>>(bhist, bbase, gcur);
  bucket_scatter_kernel<<<chunk_blocks, 256, 0, stream>>>(src, dst, gcur, packed, E);
  bucket_place_kernel<<<NBK, 256, 0, stream>>>(packed, bbase, start, segend, srcs, N);

  // ---- layer 0 ----
  colminmax_kernel<<<256, 256, 0, stream>>>(x0, mm0, mh, N);
  aggregate_kernel<<<agg_grid, 256, 0, stream>>>(x0, mh, start, segend, srcs,
                                                 tptr, 0, mm0, h0, N);
  gemm1_kernel<<<row_blocks, 256, 0, stream>>>(h0, W1, b1, h1, bn0, N, mm1, bn1);
  gemm2_kernel<<<row_blocks, 256, 0, stream>>>(h1, bn0, gamma, beta, 0, W2, b2,
                                               out, N, mm1, mh);
  // ---- layer 1 ----
  aggregate_kernel<<<agg_grid, 256, 0, stream>>>(out, mh, start, segend, srcs,
                                                 tptr, 1, mm1, h0, N);
  gemm1_kernel<<<row_blocks, 256, 0, stream>>>(h0, W1 + 8192, b1 + 128, h1, bn1, N,
                                               (unsigned*)0, (float*)0);
  gemm2_kernel<<<row_blocks, 256, 0, stream>>>(h1, bn1, gamma, beta, 1, W2 + 8192,
                                               b2 + 64, out, N,
                                               (unsigned*)0, (unsigned short*)0);
}

// Round 8
// 335.405 us; speedup vs baseline: 1.0842x; 1.0842x over previous
//
#include <hip/hip_runtime.h>
#include <math.h>

#define NN 50000
#define EPSM 1e-7f
#define BN_EPS 1e-5f
#define NBK 391                 // ceil(50000/128) buckets of 128 nodes
#define LOG2E 1.44269504088896340736f

// ---------------- bucket-sorted CSR build (line-coalesced writes) ----------------

// global bucket histogram via LDS pre-reduction; block 0 seeds layer-0 mm/bn
__global__ __launch_bounds__(256) void bucket_hist_kernel(
    const int* __restrict__ dst, int* __restrict__ bhist, int E,
    unsigned* __restrict__ mm0, float* __restrict__ bn0){
  __shared__ int h[NBK];
  int t = threadIdx.x;
  if (blockIdx.x == 0){
    if (t < 64) mm0[t] = 0x7F7FFFFFu;      // colmin seed = FLT_MAX
    else if (t < 128) mm0[t] = 0u;         // colmax seed = 0
    bn0[t] = 0.f;
  }
  for (int i = t; i < NBK; i += 256) h[i] = 0;
  __syncthreads();
  int e0 = blockIdx.x * 4096;
  int cnt = min(4096, E - e0);
  for (int i = t; i < cnt; i += 256) atomicAdd(&h[dst[e0 + i] >> 7], 1);
  __syncthreads();
  for (int i = t; i < NBK; i += 256) if (h[i]) atomicAdd(&bhist[i], h[i]);
}

// one-wave exclusive scan of 391 bucket counts -> bbase[392], gcur
__global__ void bucket_scan_kernel(const int* __restrict__ bhist,
                                   int* __restrict__ bbase, int* __restrict__ gcur){
  int lane = threadIdx.x;   // 64 threads
  int loc[7]; int s = 0;
#pragma unroll
  for (int k = 0; k < 7; ++k){
    int i = lane * 7 + k;
    int v = (i < NBK) ? bhist[i] : 0;
    loc[k] = s; s += v;
  }
  int sc = s;
#pragma unroll
  for (int o = 1; o < 64; o <<= 1){
    int n = __shfl_up(sc, o);
    if (lane >= o) sc += n;
  }
  int exc = sc - s;
#pragma unroll
  for (int k = 0; k < 7; ++k){
    int i = lane * 7 + k;
    if (i < NBK){ bbase[i] = exc + loc[k]; gcur[i] = exc + loc[k]; }
    else if (i == NBK) bbase[i] = exc + loc[k];   // total == E
  }
}

// pass 1: LDS-reorder 4096-edge chunks by bucket, burst-write packed (dst<<16|src)
__global__ __launch_bounds__(256) void bucket_scatter_kernel(
    const int* __restrict__ src, const int* __restrict__ dst,
    int* __restrict__ gcur, unsigned* __restrict__ packed_g, int E){
  __shared__ int hist[NBK], offs[NBK], gb[NBK], curk[NBK];
  __shared__ unsigned stage[4096];
  __shared__ int gpos[4096];
  int t = threadIdx.x;
  for (int i = t; i < NBK; i += 256) hist[i] = 0;
  __syncthreads();
  int e0 = blockIdx.x * 4096;
  int cnt = min(4096, E - e0);
  unsigned pk[16]; int bk[16];
  int nmine = 0;
  for (int i = t; i < cnt; i += 256){
    int d = dst[e0 + i], s = src[e0 + i];
    pk[nmine] = ((unsigned)d << 16) | (unsigned)s;
    bk[nmine] = d >> 7;
    atomicAdd(&hist[bk[nmine]], 1);
    ++nmine;
  }
  __syncthreads();
  if (t < 64){                      // wave-0 scan of 391 counts (7 per lane)
    int loc[7]; int s = 0;
#pragma unroll
    for (int k = 0; k < 7; ++k){
      int i = t * 7 + k;
      int v = (i < NBK) ? hist[i] : 0;
      loc[k] = s; s += v;
    }
    int sc = s;
#pragma unroll
    for (int o = 1; o < 64; o <<= 1){
      int n = __shfl_up(sc, o);
      if (t >= o) sc += n;
    }
    int exc = sc - s;
#pragma unroll
    for (int k = 0; k < 7; ++k){
      int i = t * 7 + k;
      if (i < NBK) offs[i] = exc + loc[k];
    }
  }
  __syncthreads();
  for (int i = t; i < NBK; i += 256){
    int h = hist[i];
    gb[i] = h ? atomicAdd(&gcur[i], h) : 0;
    curk[i] = offs[i];
  }
  __syncthreads();
  for (int k = 0; k < nmine; ++k){
    int b = bk[k];
    int p = atomicAdd(&curk[b], 1);
    stage[p] = pk[k];
    gpos[p] = gb[b] + (p - offs[b]);
  }
  __syncthreads();
  for (int j = t; j < cnt; j += 256) packed_g[gpos[j]] = stage[j];   // run-coalesced
}

// pass 2: one block per bucket — per-node offsets, start/end, coalesced srcs write
__global__ __launch_bounds__(256) void bucket_place_kernel(
    const unsigned* __restrict__ packed_g, const int* __restrict__ bbase,
    int* __restrict__ start_g, int* __restrict__ end_g,
    unsigned short* __restrict__ srcs_g, int N){
  __shared__ int deg[128], off[128], cur[128];
  __shared__ int sstage[4096];
  int b = blockIdx.x, t = threadIdx.x;
  int beg = bbase[b], cnt = bbase[b + 1] - beg;
  if (t < 128) deg[t] = 0;
  __syncthreads();
  for (int j = t; j < cnt; j += 256)
    atomicAdd(&deg[(packed_g[beg + j] >> 16) & 127], 1);
  __syncthreads();
  if (t < 64){                      // wave-0 scan of 128 (2 per lane)
    int i0 = t * 2;
    int v0 = deg[i0], v1 = deg[i0 + 1];
    int s = v0 + v1;
    int sc = s;
#pragma unroll
    for (int o = 1; o < 64; o <<= 1){
      int n = __shfl_up(sc, o);
      if (t >= o) sc += n;
    }
    int exc = sc - s;
    off[i0] = exc; off[i0 + 1] = exc + v0;
  }
  __syncthreads();
  int node0 = b * 128;
  if (t < 128){
    int node = node0 + t;
    if (node < N){
      start_g[node] = beg + off[t];
      end_g[node] = beg + off[t] + deg[t];
    }
    cur[t] = off[t];
  }
  __syncthreads();
  if (cnt <= 4096){
    for (int j = t; j < cnt; j += 256){
      unsigned p = packed_g[beg + j];
      int lp = atomicAdd(&cur[(p >> 16) & 127], 1);
      sstage[lp] = (int)(p & 0xFFFFu);
    }
    __syncthreads();
    for (int j = t; j < cnt; j += 256)
      srcs_g[beg + j] = (unsigned short)sstage[j];   // coalesced
  } else {                          // freak-bucket fallback (never for random graph)
    for (int j = t; j < cnt; j += 256){
      unsigned p = packed_g[beg + j];
      int lp = atomicAdd(&cur[(p >> 16) & 127], 1);
      srcs_g[beg + lp] = (unsigned short)(p & 0xFFFFu);
    }
  }
}

// ---------------- layer-0 only: bf16 message table [node][64] + column min/max ----

__global__ __launch_bounds__(256) void colminmax_kernel(
    const float* __restrict__ x, unsigned* __restrict__ mm,
    unsigned short* __restrict__ mh, int N){
  __shared__ unsigned smn[256], smx[256];
  int c = threadIdx.x & 63;
  int slot = blockIdx.x * 4 + (threadIdx.x >> 6);
  float mx = 0.f, mn = 1e30f;
  for (int r = slot; r < N; r += 256 * 4){
    float m = fmaxf(x[r * 64 + c], 0.f) + EPSM;
    unsigned u = __float_as_uint(m);
    u += 0x7FFFu + ((u >> 16) & 1u);         // RNE to bf16
    unsigned short us = (unsigned short)(u >> 16);
    mh[r * 64 + c] = us;
    float mb = __uint_as_float(((unsigned)us) << 16);
    mx = fmaxf(mx, mb);
    mn = fminf(mn, mb);
  }
  smn[threadIdx.x] = __float_as_uint(mn);
  smx[threadIdx.x] = __float_as_uint(mx);
  __syncthreads();
  if (threadIdx.x < 64){
    unsigned a = smn[c], b = smn[c + 64], d = smn[c + 128], e = smn[c + 192];
    atomicMin(&mm[c], min(min(a, b), min(d, e)));
    a = smx[c]; b = smx[c + 64]; d = smx[c + 128]; e = smx[c + 192];
    atomicMax(&mm[64 + c], max(max(a, b), max(d, e)));
  }
}

// ------------- single-pass softmax aggregation -------------
// wave = 2 edge slots x 32 lanes; each lane loads a uint = 2 bf16 channels, so
// one gather instruction covers a full 128 B row per edge. exp2-domain (native
// v_exp_f32): logit2 = m*t2, bound B2 = max(t2*mx, t2*mn); ratio is exact.

__global__ __launch_bounds__(256) void aggregate_kernel(
    const float* __restrict__ x, const unsigned* __restrict__ mh32,
    const int* __restrict__ start, const int* __restrict__ segend,
    const unsigned short* __restrict__ srcs, const float* __restrict__ tptr,
    int layer, const unsigned* __restrict__ mm, float* __restrict__ h0, int N){
  int node = blockIdx.x * 4 + (threadIdx.x >> 6);
  if (node >= N) return;
  int lane = threadIdx.x & 63;
  int half = lane >> 5, cp = lane & 31;     // channel pair (2cp, 2cp+1)
  float t2 = tptr[layer] * LOG2E;
  float mnL = __uint_as_float(mm[2 * cp]);
  float mxL = __uint_as_float(mm[64 + 2 * cp]);
  float mnH = __uint_as_float(mm[2 * cp + 1]);
  float mxH = __uint_as_float(mm[64 + 2 * cp + 1]);
  float BL = fmaxf(t2 * mxL, t2 * mnL);     // upper bound in log2 domain
  float BH = fmaxf(t2 * mxH, t2 * mnH);
  int beg = start[node], end = segend[node];
  float dL0=0.f,dL1=0.f,dL2=0.f,dL3=0.f, nL0=0.f,nL1=0.f,nL2=0.f,nL3=0.f;
  float dH0=0.f,dH1=0.f,dH2=0.f,dH3=0.f, nH0=0.f,nH1=0.f,nH2=0.f,nH3=0.f;
  int e = beg + half;                       // slot 0: even offsets, slot 1: odd
  for (; e + 6 < end; e += 8){
    int s0 = srcs[e], s1 = srcs[e + 2], s2 = srcs[e + 4], s3 = srcs[e + 6];
    unsigned u0 = mh32[s0 * 32 + cp], u1 = mh32[s1 * 32 + cp];
    unsigned u2 = mh32[s2 * 32 + cp], u3 = mh32[s3 * 32 + cp];
    float mL0 = __uint_as_float(u0 << 16), mH0 = __uint_as_float(u0 & 0xFFFF0000u);
    float mL1 = __uint_as_float(u1 << 16), mH1 = __uint_as_float(u1 & 0xFFFF0000u);
    float mL2 = __uint_as_float(u2 << 16), mH2 = __uint_as_float(u2 & 0xFFFF0000u);
    float mL3 = __uint_as_float(u3 << 16), mH3 = __uint_as_float(u3 & 0xFFFF0000u);
    float pL0 = exp2f(mL0 * t2 - BL), pH0 = exp2f(mH0 * t2 - BH);
    float pL1 = exp2f(mL1 * t2 - BL), pH1 = exp2f(mH1 * t2 - BH);
    float pL2 = exp2f(mL2 * t2 - BL), pH2 = exp2f(mH2 * t2 - BH);
    float pL3 = exp2f(mL3 * t2 - BL), pH3 = exp2f(mH3 * t2 - BH);
    dL0 += pL0; nL0 += mL0 * pL0;  dH0 += pH0; nH0 += mH0 * pH0;
    dL1 += pL1; nL1 += mL1 * pL1;  dH1 += pH1; nH1 += mH1 * pH1;
    dL2 += pL2; nL2 += mL2 * pL2;  dH2 += pH2; nH2 += mH2 * pH2;
    dL3 += pL3; nL3 += mL3 * pL3;  dH3 += pH3; nH3 += mH3 * pH3;
  }
  for (; e < end; e += 2){
    int s = srcs[e];
    unsigned u = mh32[s * 32 + cp];
    float mL = __uint_as_float(u << 16), mH = __uint_as_float(u & 0xFFFF0000u);
    float pL = exp2f(mL * t2 - BL), pH = exp2f(mH * t2 - BH);
    dL0 += pL; nL0 += mL * pL;  dH0 += pH; nH0 += mH * pH;
  }
  float dL = (dL0 + dL1) + (dL2 + dL3), nL = (nL0 + nL1) + (nL2 + nL3);
  float dH = (dH0 + dH1) + (dH2 + dH3), nH = (nH0 + nH1) + (nH2 + nH3);
  dL += __shfl_xor(dL, 32); nL += __shfl_xor(nL, 32);
  dH += __shfl_xor(dH, 32); nH += __shfl_xor(nH, 32);
  if (half == 0){
    float2 xv = ((const float2*)x)[node * 32 + cp];
    float2 o;
    o.x = nL / (dL + 1e-16f) + xv.x;
    o.y = nH / (dH + 1e-16f) + xv.y;
    ((float2*)h0)[node * 32 + cp] = o;
  }
}

// ---------------- MLP ----------------

// h1 = h0 @ W1 + b1 ; fused BN sum/sumsq; layer-0 block 0 seeds next mm/bn
__global__ __launch_bounds__(256) void gemm1_kernel(
    const float* __restrict__ h0, const float* __restrict__ W1,
    const float* __restrict__ b1, float* __restrict__ h1,
    float* __restrict__ bn, int N,
    unsigned* __restrict__ mm_next, float* __restrict__ bn_next){
  __shared__ float a_lds[64 * 68];
  __shared__ float w_lds[64 * 128];
  int t = threadIdx.x;
  if (mm_next != 0 && blockIdx.x == 0){
    if (t < 64) mm_next[t] = 0x7F7FFFFFu;
    else if (t < 128) mm_next[t] = 0u;
    bn_next[t] = 0.f;
  }
  const float4* wg = (const float4*)W1;
  float4* wl = (float4*)w_lds;
#pragma unroll
  for (int i = 0; i < 8; ++i) wl[t + 256 * i] = wg[t + 256 * i];
  int row0 = blockIdx.x * 64;
#pragma unroll
  for (int i = 0; i < 4; ++i){
    int li = t + 256 * i;
    int r = li >> 4, q = li & 15;
    int gr = row0 + r;
    float4 v = make_float4(0.f, 0.f, 0.f, 0.f);
    if (gr < N) v = ((const float4*)h0)[gr * 16 + q];
    *(float4*)&a_lds[r * 68 + q * 4] = v;
  }
  __syncthreads();
  int tc = t & 31, tr = t >> 5;
  float4 bias = ((const float4*)b1)[tc];
  float acc[8][4];
#pragma unroll
  for (int r = 0; r < 8; ++r){
    acc[r][0] = bias.x; acc[r][1] = bias.y; acc[r][2] = bias.z; acc[r][3] = bias.w;
  }
  for (int k = 0; k < 64; k += 4){
    float4 w0 = *(const float4*)&w_lds[(k + 0) * 128 + tc * 4];
    float4 w1 = *(const float4*)&w_lds[(k + 1) * 128 + tc * 4];
    float4 w2 = *(const float4*)&w_lds[(k + 2) * 128 + tc * 4];
    float4 w3 = *(const float4*)&w_lds[(k + 3) * 128 + tc * 4];
#pragma unroll
    for (int r = 0; r < 8; ++r){
      float4 a = *(const float4*)&a_lds[(tr * 8 + r) * 68 + k];
      acc[r][0] += a.x * w0.x + a.y * w1.x + a.z * w2.x + a.w * w3.x;
      acc[r][1] += a.x * w0.y + a.y * w1.y + a.z * w2.y + a.w * w3.y;
      acc[r][2] += a.x * w0.z + a.y * w1.z + a.z * w2.z + a.w * w3.z;
      acc[r][3] += a.x * w0.w + a.y * w1.w + a.z * w2.w + a.w * w3.w;
    }
  }
  float s[4] = {0.f, 0.f, 0.f, 0.f}, s2[4] = {0.f, 0.f, 0.f, 0.f};
#pragma unroll
  for (int r = 0; r < 8; ++r){
    int gr = row0 + tr * 8 + r;
    if (gr < N){
      *(float4*)&h1[gr * 128 + tc * 4] =
          make_float4(acc[r][0], acc[r][1], acc[r][2], acc[r][3]);
#pragma unroll
      for (int j = 0; j < 4; ++j){ s[j] += acc[r][j]; s2[j] += acc[r][j] * acc[r][j]; }
    }
  }
  __syncthreads();
  float* red = a_lds;
  if (t < 256){ red[t] = 0.f; }
  __syncthreads();
#pragma unroll
  for (int j = 0; j < 4; ++j){
    atomicAdd(&red[tc * 4 + j], s[j]);
    atomicAdd(&red[128 + tc * 4 + j], s2[j]);
  }
  __syncthreads();
  if (t < 256) atomicAdd(&bn[t], red[t]);
}

// xout = relu( relu(BN(h1)) @ W2 + b2 ). Layer 0 also emits next layer's bf16
// message table [node][64] (xout >= 0 so m = xout + eps) and column min/max.
__global__ __launch_bounds__(256) void gemm2_kernel(
    const float* __restrict__ h1, const float* __restrict__ bn,
    const float* __restrict__ gamma, const float* __restrict__ beta, int layer,
    const float* __restrict__ W2, const float* __restrict__ b2,
    float* __restrict__ xout, int N,
    unsigned* __restrict__ mm_next, unsigned short* __restrict__ mh_next){
  __shared__ float a_lds[64 * 132];
  __shared__ float w_lds[128 * 68];
  __shared__ float ss[256];     // scale[128], shift[128]
  __shared__ unsigned smn[64], smx[64];
  int t = threadIdx.x;
  if (t < 128){
    float mean = bn[t] * (1.f / (float)N);
    float var = bn[128 + t] * (1.f / (float)N) - mean * mean;
    var = fmaxf(var, 0.f);
    float sc = gamma[layer * 128 + t] / sqrtf(var + BN_EPS);
    ss[t] = sc;
    ss[128 + t] = beta[layer * 128 + t] - mean * sc;
  }
  if (t < 64){ smn[t] = 0x7F7FFFFFu; smx[t] = 0u; }
  const float4* wg = (const float4*)W2;
#pragma unroll
  for (int i = 0; i < 8; ++i){
    int li = t + 256 * i;
    int k = li >> 4, q = li & 15;
    *(float4*)&w_lds[k * 68 + q * 4] = wg[li];
  }
  __syncthreads();
  int row0 = blockIdx.x * 64;
#pragma unroll
  for (int i = 0; i < 8; ++i){
    int li = t + 256 * i;
    int r = li >> 5, q = li & 31;
    int gr = row0 + r;
    float4 v = make_float4(0.f, 0.f, 0.f, 0.f);
    if (gr < N) v = ((const float4*)h1)[gr * 32 + q];
    float4 sc = *(const float4*)&ss[q * 4];
    float4 sh = *(const float4*)&ss[128 + q * 4];
    v.x = fmaxf(v.x * sc.x + sh.x, 0.f);
    v.y = fmaxf(v.y * sc.y + sh.y, 0.f);
    v.z = fmaxf(v.z * sc.z + sh.z, 0.f);
    v.w = fmaxf(v.w * sc.w + sh.w, 0.f);
    *(float4*)&a_lds[r * 132 + q * 4] = v;
  }
  __syncthreads();
  int tc = t & 15, tr = t >> 4;
  float4 bias = ((const float4*)b2)[tc];
  float acc[4][4];
#pragma unroll
  for (int r = 0; r < 4; ++r){
    acc[r][0] = bias.x; acc[r][1] = bias.y; acc[r][2] = bias.z; acc[r][3] = bias.w;
  }
  for (int k = 0; k < 128; k += 4){
    float4 w0 = *(const float4*)&w_lds[(k + 0) * 68 + tc * 4];
    float4 w1 = *(const float4*)&w_lds[(k + 1) * 68 + tc * 4];
    float4 w2 = *(const float4*)&w_lds[(k + 2) * 68 + tc * 4];
    float4 w3 = *(const float4*)&w_lds[(k + 3) * 68 + tc * 4];
#pragma unroll
    for (int r = 0; r < 4; ++r){
      float4 a = *(const float4*)&a_lds[(tr * 4 + r) * 132 + k];
      acc[r][0] += a.x * w0.x + a.y * w1.x + a.z * w2.x + a.w * w3.x;
      acc[r][1] += a.x * w0.y + a.y * w1.y + a.z * w2.y + a.w * w3.y;
      acc[r][2] += a.x * w0.z + a.y * w1.z + a.z * w2.z + a.w * w3.z;
      acc[r][3] += a.x * w0.w + a.y * w1.w + a.z * w2.w + a.w * w3.w;
    }
  }
  unsigned mnv[4] = {0x7F7FFFFFu, 0x7F7FFFFFu, 0x7F7FFFFFu, 0x7F7FFFFFu};
  unsigned mxv[4] = {0u, 0u, 0u, 0u};
#pragma unroll
  for (int r = 0; r < 4; ++r){
    int gr = row0 + tr * 4 + r;
    if (gr < N){
      float o0 = fmaxf(acc[r][0], 0.f), o1 = fmaxf(acc[r][1], 0.f);
      float o2 = fmaxf(acc[r][2], 0.f), o3 = fmaxf(acc[r][3], 0.f);
      *(float4*)&xout[gr * 64 + tc * 4] = make_float4(o0, o1, o2, o3);
      if (mh_next != 0){
        unsigned us[4];
        float ov[4] = {o0, o1, o2, o3};
#pragma unroll
        for (int j = 0; j < 4; ++j){
          unsigned u = __float_as_uint(ov[j] + EPSM);
          u += 0x7FFFu + ((u >> 16) & 1u);       // RNE to bf16
          us[j] = u >> 16;
          unsigned fb = us[j] << 16;              // rounded value bits (positive)
          mnv[j] = min(mnv[j], fb);
          mxv[j] = max(mxv[j], fb);
        }
        ((uint2*)mh_next)[gr * 16 + tc] =
            make_uint2(us[0] | (us[1] << 16), us[2] | (us[3] << 16));
      }
    }
  }
  if (mh_next != 0){
    __syncthreads();
#pragma unroll
    for (int j = 0; j < 4; ++j){
      atomicMin(&smn[tc * 4 + j], mnv[j]);
      atomicMax(&smx[tc * 4 + j], mxv[j]);
    }
    __syncthreads();
    if (t < 64){
      atomicMin(&mm_next[t], smn[t]);
      atomicMax(&mm_next[64 + t], smx[t]);
    }
  }
}

extern "C" void kernel_launch(void* const* d_in, const int* in_sizes, int n_in,
                              void* d_out, int out_size, void* d_ws, size_t ws_size,
                              hipStream_t stream) {
  const float* x0    = (const float*)d_in[0];
  const int*   ei    = (const int*)d_in[1];
  const float* W1    = (const float*)d_in[2];
  const float* b1    = (const float*)d_in[3];
  const float* gamma = (const float*)d_in[4];
  const float* beta  = (const float*)d_in[5];
  const float* W2    = (const float*)d_in[6];
  const float* b2    = (const float*)d_in[7];
  const float* tptr  = (const float*)d_in[8];

  const int N = NN;
  const int E = in_sizes[1] / 2;
  const int* src = ei;
  const int* dst = ei + E;

  float* ws  = (float*)d_ws;
  float* h0  = ws;                        // N*64
  float* h1  = h0 + N * 64;               // N*128
  float* bn0 = h1 + N * 128;              // 256
  float* bn1 = bn0 + 256;                 // 256
  unsigned* mm0 = (unsigned*)(bn1 + 256); // 128
  unsigned* mm1 = mm0 + 128;              // 128
  unsigned short* mh = (unsigned short*)(mm1 + 128);  // N*64 bf16, [node][64]
  int* bhist = (int*)(mh + N * 64);       // NBK
  int* bbase = bhist + NBK;               // NBK+1
  int* gcur  = bbase + NBK + 1;           // NBK
  int* start = gcur + NBK;                // N
  int* segend = start + N;                // N
  unsigned* packed = (unsigned*)(segend + N);  // E
  unsigned short* srcs = (unsigned short*)(packed + E);  // E

  float* out = (float*)d_out;

  const int row_blocks = (N + 63) / 64;
  const int chunk_blocks = (E + 4095) / 4096;
  const int agg_blocks = (N + 3) / 4;

  // ---- bucket-sorted CSR build (edge structure is layer-invariant) ----
  hipMemsetAsync(bhist, 0, NBK * sizeof(int), stream);
  bucket_hist_kernel<<<chunk_blocks, 256, 0, stream>>>(dst, bhist, E, mm0, bn0);
  bucket_scan_kernel<<<1, 64, 0, stream>>>(bhist, bbase, gcur);
  bucket_scatter_kernel<<<chunk_blocks, 256, 0, stream>>>(src, dst, gcur, packed, E);
  bucket_place_kernel<<<NBK, 256, 0, stream>>>(packed, bbase, start, segend, srcs, N);

  // ---- layer 0 ----
  colminmax_kernel<<<256, 256, 0, stream>>>(x0, mm0, mh, N);
  aggregate_kernel<<<agg_blocks, 256, 0, stream>>>(x0, (const unsigned*)mh, start,
                                                   segend, srcs, tptr, 0, mm0, h0, N);
  gemm1_kernel<<<row_blocks, 256, 0, stream>>>(h0, W1, b1, h1, bn0, N, mm1, bn1);
  gemm2_kernel<<<row_blocks, 256, 0, stream>>>(h1, bn0, gamma, beta, 0, W2, b2,
                                               out, N, mm1, mh);
  // ---- layer 1 ----
  aggregate_kernel<<<agg_blocks, 256, 0, stream>>>(out, (const unsigned*)mh, start,
                                                   segend, srcs, tptr, 1, mm1, h0, N);
  gemm1_kernel<<<row_blocks, 256, 0, stream>>>(h0, W1 + 8192, b1 + 128, h1, bn1, N,
                                               (unsigned*)0, (float*)0);
  gemm2_kernel<<<row_blocks, 256, 0, stream>>>(h1, bn1, gamma, beta, 1, W2 + 8192,
                                               b2 + 64, out, N,
                                               (unsigned*)0, (unsigned short*)0);
}